// Round 6
// baseline (131.242 us; speedup 1.0000x reference)
//
#include <hip/hip_runtime.h>

typedef _Float16 half8 __attribute__((ext_vector_type(8)));
typedef float f32x4 __attribute__((ext_vector_type(4)));
typedef float f32x16 __attribute__((ext_vector_type(16)));
typedef unsigned int u32x4 __attribute__((ext_vector_type(4)));

#define NPTS 1024
#define NB 8
#define HDIM 512
#define CH 16
#define RT 1056              // 1024 pts + row 1024 = x + zero pad to 33*32

// workspace byte offsets
#define OFF_WBF 0u                         // 8*64*512*16B = 4 MB
#define OFF_A0F (4u*1024u*1024u)
#define A0SZ    (64u*RT*16u)               // 1,081,344
#define OFF_WLF (OFF_A0F + A0SZ)
#define OFF_FS  (OFF_WLF + 16384u)
#define OFF_IS  (OFF_FS + 65536u)
#define OFF_BX  (OFF_IS + 64u)
#define OFF_CT  (OFF_BX + 512u)

__device__ __forceinline__ float elu(float z) { return z > 0.f ? z : expm1f(z); }

// ---------- kPrep ----------
// blocks 0..1023   : Wb -> f16 octets [i*64+koct][n][8], 1 octet/thread
// blocks 1024..1287: a0 rows (4/block): elu(s@Wfirst+b) -> octets [koct][m][8]; f_s
// block 1288       : Wlast -> octets [hoct][ch][8]; zero Isum + done-counter
__global__ __launch_bounds__(256) void kPrep(const float* __restrict__ s,
    const float* __restrict__ x, const float* __restrict__ Wfirst,
    const float* __restrict__ bfirst, const float* __restrict__ Wb,
    const float* __restrict__ Wlast, const float* __restrict__ Wf,
    const float* __restrict__ bf,
    _Float16* __restrict__ Wbf, _Float16* __restrict__ Wlf,
    _Float16* __restrict__ a0f, float* __restrict__ f_s,
    float* __restrict__ Isum, unsigned* __restrict__ cnt) {
  __shared__ __align__(16) float sm[8192];
  int b = blockIdx.x, t = threadIdx.x;
  if (b < 1024) {
    int i = b >> 7, koct = (b >> 1) & 63, n = (b & 1) * 256 + t;
    const float* src = Wb + ((size_t)i * 512 + koct * 8) * 512 + n;
    float v[8];
#pragma unroll
    for (int j = 0; j < 8; ++j) v[j] = src[j * 512];
    union { _Float16 h[8]; u32x4 u; } hu;
#pragma unroll
    for (int j = 0; j < 8; ++j) hu.h[j] = (_Float16)v[j];
    *(u32x4*)(Wbf + ((size_t)(i * 64 + koct) * 512 + n) * 8) = hu.u;
  } else if (b < 1288) {
    int rr = t >> 6, tl = t & 63;
    int m = (b - 1024) * 4 + rr;
    float* sv = &sm[rr * 8];
    if (tl < 8) sv[tl] = (m < 1024) ? s[m * 8 + tl] : (m == 1024 ? x[tl] : 0.f);
    __syncthreads();
    size_t o = ((size_t)tl * RT + m) * 8;
    if (m <= 1024) {
      float acc[8];
#pragma unroll
      for (int jj = 0; jj < 8; ++jj) acc[jj] = bfirst[8 * tl + jj];
#pragma unroll
      for (int d = 0; d < 8; ++d) {
        float sd = sv[d];
        f32x4 w0 = *(const f32x4*)&Wfirst[d * 512 + 8 * tl];
        f32x4 w1 = *(const f32x4*)&Wfirst[d * 512 + 8 * tl + 4];
#pragma unroll
        for (int e = 0; e < 4; ++e) { acc[e] += sd * w0[e]; acc[4 + e] += sd * w1[e]; }
      }
      union { _Float16 h[8]; u32x4 u; } hu;
#pragma unroll
      for (int jj = 0; jj < 8; ++jj) hu.h[jj] = (_Float16)elu(acc[jj]);
      *(u32x4*)(a0f + o) = hu.u;
      if (m < 1024 && tl < 16) {
        float a = bf[tl];
#pragma unroll
        for (int d = 0; d < 8; ++d) a += sv[d] * Wf[d * 16 + tl];
        f_s[m * 16 + tl] = a;
      }
    } else {
      u32x4 z;
#pragma unroll
      for (int e = 0; e < 4; ++e) z[e] = 0u;
      *(u32x4*)(a0f + o) = z;
    }
  } else {
    if (t < 8) Isum[t] = 0.f;
    if (t == 8) *cnt = 0u;
#pragma unroll
    for (int it = 0; it < 32; ++it) sm[t + 256 * it] = Wlast[t + 256 * it];
    __syncthreads();
#pragma unroll
    for (int p = 0; p < 4; ++p) {
      int oi = p * 256 + t;
      int ko = oi >> 4, ch = oi & 15;
      union { _Float16 h[8]; u32x4 u; } hu;
#pragma unroll
      for (int jj = 0; jj < 8; ++jj) hu.h[jj] = (_Float16)sm[(ko * 8 + jj) * 16 + ch];
      *(u32x4*)(Wlf + oi * 8) = hu.u;
    }
  }
}

// ---------- kB: fused GEMM + elu + projection + diff^2 + mu + combine ----------
// grid 264 = i(8, ==XCD) x mt(33). Block: 32m x 512n (wave: 32m x 32n x 4 n-tiles).
// A/B straight from L1/L2, 3-slot distance-2 register pipeline, no K-loop barriers.
// Last block (device-scope counter) computes mu + final output.
__global__ __launch_bounds__(256, 2) void kB(const _Float16* __restrict__ Wbf,
    const _Float16* __restrict__ a0f, const _Float16* __restrict__ Wlf,
    const float* __restrict__ bb, const float* __restrict__ blast,
    const float* __restrict__ f_s, float* __restrict__ Isum,
    float* __restrict__ basisx, unsigned* __restrict__ cnt,
    float* __restrict__ out) {
  __shared__ u32x4 SC[512];      // 8 KB: per-wave 128 a1 octets (A-frag layout)
  __shared__ float S2[32][16];
  __shared__ float wsum[4];
  __shared__ unsigned oc;
  __shared__ float muL[8];
  int t = threadIdx.x, b = blockIdx.x;
  int i = b & 7, mt = b >> 3;
  int m0 = mt * 32;
  int w = t >> 6, lane = t & 63, ln = lane & 31, q = lane >> 5, q4 = lane >> 4;

  const u32x4* a4 = (const u32x4*)a0f;
  const u32x4* b4 = (const u32x4*)Wbf;
  int ma = m0 + ln, ib = i * 64;
  int nwl = w * 32 + ln;         // lane's n within j-tile stride 128

  f32x16 acc[4];
#pragma unroll
  for (int j = 0; j < 4; ++j)
#pragma unroll
    for (int rr = 0; rr < 16; ++rr) acc[j][rr] = 0.f;

  u32x4 pa[3][2], pb[3][2][4];
#pragma unroll
  for (int st = 0; st < 2; ++st) {
    int k0 = st * 4 + q, k1 = k0 + 2;
    pa[st][0] = a4[k0 * RT + ma];
    pa[st][1] = a4[k1 * RT + ma];
#pragma unroll
    for (int j = 0; j < 4; ++j) {
      pb[st][0][j] = b4[(size_t)(ib + k0) * 512 + nwl + 128 * j];
      pb[st][1][j] = b4[(size_t)(ib + k1) * 512 + nwl + 128 * j];
    }
  }
#pragma unroll
  for (int ks = 0; ks < 16; ++ks) {
    int sl = ks % 3;
    if (ks < 14) {
      int sn = (ks + 2) % 3;
      int k0 = (ks + 2) * 4 + q, k1 = k0 + 2;
      pa[sn][0] = a4[k0 * RT + ma];
      pa[sn][1] = a4[k1 * RT + ma];
#pragma unroll
      for (int j = 0; j < 4; ++j) {
        pb[sn][0][j] = b4[(size_t)(ib + k0) * 512 + nwl + 128 * j];
        pb[sn][1][j] = b4[(size_t)(ib + k1) * 512 + nwl + 128 * j];
      }
    }
#pragma unroll
    for (int sfx = 0; sfx < 2; ++sfx) {
      half8 aH = __builtin_bit_cast(half8, pa[sl][sfx]);
#pragma unroll
      for (int j = 0; j < 4; ++j)
        acc[j] = __builtin_amdgcn_mfma_f32_32x32x16_f16(
            aH, __builtin_bit_cast(half8, pb[sl][sfx][j]), acc[j], 0, 0, 0);
    }
  }

  // ---- epilogue ----
  ((float*)S2)[t] = 0.f;
  ((float*)S2)[t + 256] = 0.f;
  __syncthreads();               // S2 zeroed before any atomics

  _Float16* scr = (_Float16*)&SC[w * 128];
  const u32x4* s4 = &SC[w * 128];
  const u32x4* w4 = (const u32x4*)Wlf;
  int ch = lane & 15;
#pragma unroll
  for (int j = 0; j < 4; ++j) {
    int nw = w * 32 + 128 * j;
    float bcol = bb[i * 512 + nw + ln];
#pragma unroll
    for (int rr = 0; rr < 16; ++rr) {
      int row = (rr & 3) + 8 * (rr >> 2) + 4 * q;               // 32x32 C-layout row
      float a1 = elu(acc[j][rr] + bcol);
      int oi = (row >> 4) * 64 + (ln >> 3) * 16 + (row & 15);   // [mt2][koct][m16]
      scr[oi * 8 + (ln & 7)] = (_Float16)a1;
    }
    half8 wv = __builtin_bit_cast(half8, w4[(size_t)((nw >> 3) + q4) * 16 + ch]);
#pragma unroll
    for (int mt2 = 0; mt2 < 2; ++mt2) {
      f32x4 D2;
#pragma unroll
      for (int rr = 0; rr < 4; ++rr) D2[rr] = 0.f;
      half8 pv = __builtin_bit_cast(half8, s4[mt2 * 64 + q4 * 16 + ch]);
      D2 = __builtin_amdgcn_mfma_f32_16x16x32_f16(pv, wv, D2, 0, 0, 0);
#pragma unroll
      for (int rr = 0; rr < 4; ++rr)
        atomicAdd(&S2[mt2 * 16 + q4 * 4 + rr][ch], D2[rr]);
    }
  }
  __syncthreads();

  if (mt == 32) {
    // x-row (local row 0 == global row 1024); rows 1+ are zero padding
    if (t < 16) basisx[i * 16 + t] = S2[0][t] + blast[t];
  } else {
    float loc = 0.f;
#pragma unroll
    for (int p = 0; p < 2; ++p) {
      int item = t + p * 256;
      int ml = item >> 4, c2 = item & 15;
      float bs = S2[ml][c2] + blast[c2];
      float d = f_s[(size_t)(m0 + ml) * 16 + c2] - bs;
      loc += d * d;
    }
    loc += __shfl_xor(loc, 1, 64);
    loc += __shfl_xor(loc, 2, 64);
    loc += __shfl_xor(loc, 4, 64);
    loc += __shfl_xor(loc, 8, 64);
    loc += __shfl_xor(loc, 16, 64);
    loc += __shfl_xor(loc, 32, 64);
    if (lane == 0) wsum[w] = loc;
    __syncthreads();
    if (t == 0) atomicAdd(&Isum[i], wsum[0] + wsum[1] + wsum[2] + wsum[3]);
  }

  // ---- done-count; 264th block computes mu + final combine ----
  if (t == 0) {
    __threadfence();
    oc = atomicAdd(cnt, 1u);
  }
  __syncthreads();
  if (oc == 263) {
    __threadfence();
    if (t < 8) {
      float S = atomicAdd(&Isum[t], 0.f);        // device-scope atomic read
      float nb = 0.5f * sqrtf(S);                 // sqrt(VOLUME/NPTS * S) = sqrt(S/4)
      muL[t] = (nb <= 1000.0f) ? nb : 0.f;
    }
    __syncthreads();
    if (t < 128) {
      int c2 = t & 15;
      float num = 0.f, den = 1e-7f;
#pragma unroll
      for (int ii = 0; ii < NB; ++ii) {
        float bx = atomicAdd(&basisx[ii * 16 + c2], 0.f);   // atomic read
        num += muL[ii] * bx;
        den += muL[ii];
      }
      out[t] = num / den;
    }
  }
}

extern "C" void kernel_launch(void* const* d_in, const int* in_sizes, int n_in,
                              void* d_out, int out_size, void* d_ws, size_t ws_size,
                              hipStream_t stream) {
  const float* s      = (const float*)d_in[0];
  const float* x      = (const float*)d_in[1];
  const float* Wfirst = (const float*)d_in[2];
  const float* bfirst = (const float*)d_in[3];
  const float* Wb     = (const float*)d_in[4];
  const float* bb     = (const float*)d_in[5];
  const float* Wlast  = (const float*)d_in[6];
  const float* blast  = (const float*)d_in[7];
  const float* Wf     = (const float*)d_in[8];
  const float* bf     = (const float*)d_in[9];

  char* ws = (char*)d_ws;
  _Float16* Wbf = (_Float16*)(ws + OFF_WBF);
  _Float16* a0f = (_Float16*)(ws + OFF_A0F);
  _Float16* Wlf = (_Float16*)(ws + OFF_WLF);
  float* f_s    = (float*)(ws + OFF_FS);
  float* Isum   = (float*)(ws + OFF_IS);
  float* basisx = (float*)(ws + OFF_BX);
  unsigned* cnt = (unsigned*)(ws + OFF_CT);
  float* out    = (float*)d_out;

  kPrep<<<1289, 256, 0, stream>>>(s, x, Wfirst, bfirst, Wb, Wlast, Wf, bf,
                                  Wbf, Wlf, a0f, f_s, Isum, cnt);
  kB<<<264, 256, 0, stream>>>(Wbf, a0f, Wlf, bb, blast, f_s, Isum, basisx, cnt, out);
}

// Round 7
// 126.621 us; speedup vs baseline: 1.0365x; 1.0365x over previous
//
#include <hip/hip_runtime.h>

typedef _Float16 half8 __attribute__((ext_vector_type(8)));
typedef float f32x4 __attribute__((ext_vector_type(4)));
typedef float f32x16 __attribute__((ext_vector_type(16)));
typedef unsigned int u32x4 __attribute__((ext_vector_type(4)));

#define NPTS 1024
#define NB 8
#define HDIM 512
#define CH 16
#define RT 1056              // 1024 pts + row 1024 = x + zero pad to 33*32

// workspace byte offsets
#define OFF_WBF 0u                         // 8*64*512*16B = 4 MB
#define OFF_A0F (4u*1024u*1024u)
#define A0SZ    (64u*RT*16u)               // 1,081,344
#define OFF_WLF (OFF_A0F + A0SZ)
#define OFF_FS  (OFF_WLF + 16384u)
#define OFF_IS  (OFF_FS + 65536u)
#define OFF_BX  (OFF_IS + 64u)
#define OFF_CT  (OFF_BX + 512u)

__device__ __forceinline__ float elu(float z) { return z > 0.f ? z : expm1f(z); }

// ---------- kPrep ----------
// blocks 0..1023   : Wb -> f16 octets [i*64+koct][n][8], 1 octet/thread
// blocks 1024..1287: a0 rows (4/block): elu(s@Wfirst+b) -> octets [koct][m][8]; f_s
// block 1288       : Wlast -> octets [hoct][ch][8]; zero Isum + done-counter
__global__ __launch_bounds__(256) void kPrep(const float* __restrict__ s,
    const float* __restrict__ x, const float* __restrict__ Wfirst,
    const float* __restrict__ bfirst, const float* __restrict__ Wb,
    const float* __restrict__ Wlast, const float* __restrict__ Wf,
    const float* __restrict__ bf,
    _Float16* __restrict__ Wbf, _Float16* __restrict__ Wlf,
    _Float16* __restrict__ a0f, float* __restrict__ f_s,
    float* __restrict__ Isum, unsigned* __restrict__ cnt) {
  __shared__ __align__(16) float sm[8192];
  int b = blockIdx.x, t = threadIdx.x;
  if (b < 1024) {
    int i = b >> 7, koct = (b >> 1) & 63, n = (b & 1) * 256 + t;
    const float* src = Wb + ((size_t)i * 512 + koct * 8) * 512 + n;
    float v[8];
#pragma unroll
    for (int j = 0; j < 8; ++j) v[j] = src[j * 512];
    union { _Float16 h[8]; u32x4 u; } hu;
#pragma unroll
    for (int j = 0; j < 8; ++j) hu.h[j] = (_Float16)v[j];
    *(u32x4*)(Wbf + ((size_t)(i * 64 + koct) * 512 + n) * 8) = hu.u;
  } else if (b < 1288) {
    int rr = t >> 6, tl = t & 63;
    int m = (b - 1024) * 4 + rr;
    float* sv = &sm[rr * 8];
    if (tl < 8) sv[tl] = (m < 1024) ? s[m * 8 + tl] : (m == 1024 ? x[tl] : 0.f);
    __syncthreads();
    size_t o = ((size_t)tl * RT + m) * 8;
    if (m <= 1024) {
      float acc[8];
#pragma unroll
      for (int jj = 0; jj < 8; ++jj) acc[jj] = bfirst[8 * tl + jj];
#pragma unroll
      for (int d = 0; d < 8; ++d) {
        float sd = sv[d];
        f32x4 w0 = *(const f32x4*)&Wfirst[d * 512 + 8 * tl];
        f32x4 w1 = *(const f32x4*)&Wfirst[d * 512 + 8 * tl + 4];
#pragma unroll
        for (int e = 0; e < 4; ++e) { acc[e] += sd * w0[e]; acc[4 + e] += sd * w1[e]; }
      }
      union { _Float16 h[8]; u32x4 u; } hu;
#pragma unroll
      for (int jj = 0; jj < 8; ++jj) hu.h[jj] = (_Float16)elu(acc[jj]);
      *(u32x4*)(a0f + o) = hu.u;
      if (m < 1024 && tl < 16) {
        float a = bf[tl];
#pragma unroll
        for (int d = 0; d < 8; ++d) a += sv[d] * Wf[d * 16 + tl];
        f_s[m * 16 + tl] = a;
      }
    } else {
      u32x4 z;
#pragma unroll
      for (int e = 0; e < 4; ++e) z[e] = 0u;
      *(u32x4*)(a0f + o) = z;
    }
  } else {
    if (t < 8) Isum[t] = 0.f;
    if (t == 8) *cnt = 0u;
#pragma unroll
    for (int it = 0; it < 32; ++it) sm[t + 256 * it] = Wlast[t + 256 * it];
    __syncthreads();
#pragma unroll
    for (int p = 0; p < 4; ++p) {
      int oi = p * 256 + t;
      int ko = oi >> 4, ch = oi & 15;
      union { _Float16 h[8]; u32x4 u; } hu;
#pragma unroll
      for (int jj = 0; jj < 8; ++jj) hu.h[jj] = (_Float16)sm[(ko * 8 + jj) * 16 + ch];
      *(u32x4*)(Wlf + oi * 8) = hu.u;
    }
  }
}

// ---------- kB: fused GEMM + elu + projection + diff^2 + mu + combine ----------
// grid 264 = i(8, ==XCD) x mt(33). Block: 1024 thr = 16 waves; wave w owns 32m x 32n
// (n-tile w). A shared by all 16 waves (L1 reuse); 4-slot distance-3 register
// pipeline; no K-loop barriers. Last block (device counter) does mu + combine.
__global__ __launch_bounds__(1024, 4) void kB(const _Float16* __restrict__ Wbf,
    const _Float16* __restrict__ a0f, const _Float16* __restrict__ Wlf,
    const float* __restrict__ bb, const float* __restrict__ blast,
    const float* __restrict__ f_s, float* __restrict__ Isum,
    float* __restrict__ basisx, unsigned* __restrict__ cnt,
    float* __restrict__ out) {
  __shared__ u32x4 SC[2048];     // 32 KB: per-wave 128 a1 octets (A-frag layout)
  __shared__ float S2[32][16];
  __shared__ float wsum[16];
  __shared__ unsigned oc;
  __shared__ float muL[8];
  int t = threadIdx.x, b = blockIdx.x;
  int i = b & 7, mt = b >> 3;
  int m0 = mt * 32;
  int w = t >> 6, lane = t & 63, ln = lane & 31, q = lane >> 5, q4 = lane >> 4;
  int nw = w * 32;

  const u32x4* a4 = (const u32x4*)a0f;
  const u32x4* b4 = (const u32x4*)Wbf;
  int ma = m0 + ln, nb = nw + ln, ib = i * 64;

  f32x16 acc;
#pragma unroll
  for (int rr = 0; rr < 16; ++rr) acc[rr] = 0.f;

  u32x4 pa[4][2], pb[4][2];
#pragma unroll
  for (int st = 0; st < 3; ++st) {
    int k0 = st * 4 + q, k1 = k0 + 2;
    pa[st][0] = a4[k0 * RT + ma];
    pa[st][1] = a4[k1 * RT + ma];
    pb[st][0] = b4[(size_t)(ib + k0) * 512 + nb];
    pb[st][1] = b4[(size_t)(ib + k1) * 512 + nb];
  }
#pragma unroll
  for (int ks = 0; ks < 16; ++ks) {
    int sl = ks & 3;
    acc = __builtin_amdgcn_mfma_f32_32x32x16_f16(
        __builtin_bit_cast(half8, pa[sl][0]), __builtin_bit_cast(half8, pb[sl][0]), acc, 0, 0, 0);
    acc = __builtin_amdgcn_mfma_f32_32x32x16_f16(
        __builtin_bit_cast(half8, pa[sl][1]), __builtin_bit_cast(half8, pb[sl][1]), acc, 0, 0, 0);
    if (ks < 13) {
      int sn = (ks + 3) & 3;
      int k0 = (ks + 3) * 4 + q, k1 = k0 + 2;
      pa[sn][0] = a4[k0 * RT + ma];
      pa[sn][1] = a4[k1 * RT + ma];
      pb[sn][0] = b4[(size_t)(ib + k0) * 512 + nb];
      pb[sn][1] = b4[(size_t)(ib + k1) * 512 + nb];
    }
  }

  // ---- epilogue: bias+elu -> f16 A-frags in per-wave LDS, project, reduce ----
  if (t < 512) ((float*)S2)[t] = 0.f;
  __syncthreads();               // S2 zeroed before any atomics

  float bcol = bb[i * 512 + nw + ln];
  _Float16* scr = (_Float16*)&SC[w * 128];
#pragma unroll
  for (int rr = 0; rr < 16; ++rr) {
    int row = (rr & 3) + 8 * (rr >> 2) + 4 * q;               // 32x32 C-layout row
    float a1 = elu(acc[rr] + bcol);
    int oi = (row >> 4) * 64 + (ln >> 3) * 16 + (row & 15);   // [mt2][koct][m16]
    scr[oi * 8 + (ln & 7)] = (_Float16)a1;
  }
  __syncthreads();

  const u32x4* s4 = &SC[w * 128];
  const u32x4* w4 = (const u32x4*)Wlf;
  int ch = lane & 15;
  half8 wv = __builtin_bit_cast(half8, w4[(size_t)((nw >> 3) + q4) * 16 + ch]);
#pragma unroll
  for (int mt2 = 0; mt2 < 2; ++mt2) {
    f32x4 D2;
#pragma unroll
    for (int rr = 0; rr < 4; ++rr) D2[rr] = 0.f;
    half8 pv = __builtin_bit_cast(half8, s4[mt2 * 64 + q4 * 16 + ch]);
    D2 = __builtin_amdgcn_mfma_f32_16x16x32_f16(pv, wv, D2, 0, 0, 0);
#pragma unroll
    for (int rr = 0; rr < 4; ++rr)
      atomicAdd(&S2[mt2 * 16 + q4 * 4 + rr][ch], D2[rr]);
  }
  __syncthreads();

  if (mt == 32) {
    // x-row (local row 0 == global row 1024); rows 1+ are zero padding
    if (t < 16) basisx[i * 16 + t] = S2[0][t] + blast[t];
  } else {
    float loc = 0.f;
    if (t < 512) {
      int ml = t >> 4, c2 = t & 15;
      float bs = S2[ml][c2] + blast[c2];
      float d = f_s[(size_t)(m0 + ml) * 16 + c2] - bs;
      loc = d * d;
    }
    loc += __shfl_xor(loc, 1, 64);
    loc += __shfl_xor(loc, 2, 64);
    loc += __shfl_xor(loc, 4, 64);
    loc += __shfl_xor(loc, 8, 64);
    loc += __shfl_xor(loc, 16, 64);
    loc += __shfl_xor(loc, 32, 64);
    if (lane == 0) wsum[w] = loc;
    __syncthreads();
    if (t == 0) {
      float S = 0.f;
#pragma unroll
      for (int ww = 0; ww < 16; ++ww) S += wsum[ww];
      atomicAdd(&Isum[i], S);
    }
  }

  // ---- done-count; 264th block computes mu + final combine ----
  if (t == 0) {
    __threadfence();
    oc = atomicAdd(cnt, 1u);
  }
  __syncthreads();
  if (oc == 263) {
    __threadfence();
    if (t < 8) {
      float S = atomicAdd(&Isum[t], 0.f);        // device-scope atomic read
      float nb = 0.5f * sqrtf(S);                 // sqrt(VOLUME/NPTS * S) = sqrt(S/4)
      muL[t] = (nb <= 1000.0f) ? nb : 0.f;
    }
    __syncthreads();
    if (t < 128) {
      int c2 = t & 15;
      float num = 0.f, den = 1e-7f;
#pragma unroll
      for (int ii = 0; ii < NB; ++ii) {
        float bx = atomicAdd(&basisx[ii * 16 + c2], 0.f);   // atomic read
        num += muL[ii] * bx;
        den += muL[ii];
      }
      out[t] = num / den;
    }
  }
}

extern "C" void kernel_launch(void* const* d_in, const int* in_sizes, int n_in,
                              void* d_out, int out_size, void* d_ws, size_t ws_size,
                              hipStream_t stream) {
  const float* s      = (const float*)d_in[0];
  const float* x      = (const float*)d_in[1];
  const float* Wfirst = (const float*)d_in[2];
  const float* bfirst = (const float*)d_in[3];
  const float* Wb     = (const float*)d_in[4];
  const float* bb     = (const float*)d_in[5];
  const float* Wlast  = (const float*)d_in[6];
  const float* blast  = (const float*)d_in[7];
  const float* Wf     = (const float*)d_in[8];
  const float* bf     = (const float*)d_in[9];

  char* ws = (char*)d_ws;
  _Float16* Wbf = (_Float16*)(ws + OFF_WBF);
  _Float16* a0f = (_Float16*)(ws + OFF_A0F);
  _Float16* Wlf = (_Float16*)(ws + OFF_WLF);
  float* f_s    = (float*)(ws + OFF_FS);
  float* Isum   = (float*)(ws + OFF_IS);
  float* basisx = (float*)(ws + OFF_BX);
  unsigned* cnt = (unsigned*)(ws + OFF_CT);
  float* out    = (float*)d_out;

  kPrep<<<1289, 256, 0, stream>>>(s, x, Wfirst, bfirst, Wb, Wlast, Wf, bf,
                                  Wbf, Wlf, a0f, f_s, Isum, cnt);
  kB<<<264, 1024, 0, stream>>>(Wbf, a0f, Wlf, bb, blast, f_s, Isum, basisx, cnt, out);
}